// Round 11
// baseline (1830.171 us; speedup 1.0000x reference)
//
#include <hip/hip_runtime.h>
#include <hip/hip_bf16.h>

// R11 = R9/R10 resubmitted unchanged (R9, R10 both failed on infra:
// GPUAcquisitionTimeout; kernel never executed either round).
// De-fuse rationale from R8 post-mortem: fused gather+MFMA was
// concurrency-bound (occ 43%, barrier-coupled load imbalance), not
// traffic-bound; R6's free-running k_agg8 did the same gather in 331us at
// 80% occ. Split: k_agg8 (R6 + 8/4/1 ILP) -> aggb -> k_mm2 (R6 MFMA + R8
// LDS C-tile coalesced epilogue).
// NOTE: WRITE_SIZE is contaminated by harness 0xAA ws-poison writebacks; ignore.

#define NN 100000
#define EE 3200000

typedef __attribute__((ext_vector_type(8))) short bf16x8;
typedef __attribute__((ext_vector_type(4))) float f32x4;

static __device__ __forceinline__ float frelu(float v) { return v > 0.f ? v : 0.f; }

// round-to-nearest-even f32 -> bf16 bits
static __device__ __forceinline__ unsigned short f2bf(float f) {
    unsigned b = __float_as_uint(f);
    return (unsigned short)((b + 0x7fffu + ((b >> 16) & 1u)) >> 16);
}
static __device__ __forceinline__ unsigned packbf(float lo, float hi) {
    return (unsigned)f2bf(lo) | ((unsigned)f2bf(hi) << 16);
}
static __device__ __forceinline__ float bflo(unsigned u) { return __uint_as_float(u << 16); }
static __device__ __forceinline__ float bfhi(unsigned u) { return __uint_as_float(u & 0xffff0000u); }
static __device__ __forceinline__ float bf2f(unsigned short u) {
    return __uint_as_float(((unsigned)u) << 16);
}

// ---------- x0 = bf16(node_emb[node_type_ids]) ----------
__global__ void k_gather_xb(const int* __restrict__ ntype, const float* __restrict__ nemb,
                            unsigned* __restrict__ xb) {
    int i = blockIdx.x * 256 + threadIdx.x;  // exactly N*64 threads; q covers dims 2q,2q+1
    int n = i >> 6, q = i & 63;
    int tt = ntype[n];
    float2 v = ((const float2*)(nemb + (size_t)tt * 128))[q];
    xb[(size_t)n * 64 + q] = packbf(v.x, v.y);
}

// ---------- CSR build keyed by tgt ONLY (N segments, L2-resident atomics) ----------
__global__ void k_count(const int* __restrict__ eidx, int* __restrict__ rowptr) {
    for (int e = blockIdx.x * blockDim.x + threadIdx.x; e < EE; e += gridDim.x * blockDim.x) {
        int2 p = ((const int2*)eidx)[e];
        atomicAdd(&rowptr[p.y], 1);
    }
}

__global__ void k_scan1(int* data, int* partials, int nseg) {
    __shared__ int sd[256];
    int t = threadIdx.x;
    int base = blockIdx.x * 1024 + t * 4;
    int v[4];
#pragma unroll
    for (int k = 0; k < 4; ++k) v[k] = (base + k < nseg) ? data[base + k] : 0;
    int tsum = v[0] + v[1] + v[2] + v[3];
    sd[t] = tsum;
    __syncthreads();
    for (int off = 1; off < 256; off <<= 1) {
        int add = (t >= off) ? sd[t - off] : 0;
        __syncthreads();
        sd[t] += add;
        __syncthreads();
    }
    int run = sd[t] - tsum;
#pragma unroll
    for (int k = 0; k < 4; ++k) {
        if (base + k < nseg) data[base + k] = run;
        run += v[k];
    }
    if (t == 255) partials[blockIdx.x] = sd[255];
}

__global__ void k_scan2(int* partials, int nb) {
    __shared__ int sd[1024];
    int t = threadIdx.x;
    int v = (t < nb) ? partials[t] : 0;
    sd[t] = v;
    __syncthreads();
    for (int off = 1; off < 1024; off <<= 1) {
        int add = (t >= off) ? sd[t - off] : 0;
        __syncthreads();
        sd[t] += add;
        __syncthreads();
    }
    if (t < nb) partials[t] = sd[t] - v;
}

__global__ void k_scan3(int* rowptr, const int* __restrict__ partials, int nseg) {
    int i = blockIdx.x * 256 + threadIdx.x;
    if (i < nseg) rowptr[i] += partials[i >> 10];
}

// scatter packed (src<<3)|rel; rowptr becomes inclusive segment ENDS
__global__ void k_scatter(const int* __restrict__ eidx, const int* __restrict__ etype,
                          int* rowptr, int* __restrict__ pk) {
    for (int e = blockIdx.x * blockDim.x + threadIdx.x; e < EE; e += gridDim.x * blockDim.x) {
        int2 p = ((const int2*)eidx)[e];
        int rel = etype[e];
        int pos = atomicAdd(&rowptr[p.y], 1);
        pk[pos] = (p.x << 3) | rel;
    }
}

// ---------- Wb[l][d][k] bf16: k<1024 -> relW[l][k>>7][d][k&127]; else selfW[l][d][k-1024]
__global__ void k_prepWb(const float* __restrict__ relW, const float* __restrict__ selfW,
                         unsigned short* __restrict__ Wb) {
    int idx = blockIdx.x * 256 + threadIdx.x;  // 2*128*1152 threads
    int k = idx % 1152;
    int d = (idx / 1152) & 127;
    int l = idx / (1152 * 128);
    float v;
    if (k < 1024)
        v = relW[((((size_t)l * 8) + (k >> 7)) * 128 + d) * 128 + (k & 127)];
    else
        v = selfW[((size_t)l * 128 + d) * 128 + (k - 1024)];
    Wb[idx] = f2bf(v);
}

// ---------- agg: one wave per node, all 8 relations accumulated at once ----------
static __device__ __forceinline__ void addpk(float acc[8][2], int kk, unsigned u) {
    float lo = bflo(u), hi = bfhi(u);
    switch (kk & 7) {  // wave-uniform branch (kk broadcast-loaded)
        case 0: acc[0][0] += lo; acc[0][1] += hi; break;
        case 1: acc[1][0] += lo; acc[1][1] += hi; break;
        case 2: acc[2][0] += lo; acc[2][1] += hi; break;
        case 3: acc[3][0] += lo; acc[3][1] += hi; break;
        case 4: acc[4][0] += lo; acc[4][1] += hi; break;
        case 5: acc[5][0] += lo; acc[5][1] += hi; break;
        case 6: acc[6][0] += lo; acc[6][1] += hi; break;
        case 7: acc[7][0] += lo; acc[7][1] += hi; break;
    }
}

__global__ __launch_bounds__(256) void k_agg8(const unsigned* __restrict__ xb,
                                              const int* __restrict__ rowptr,
                                              const int* __restrict__ pk,
                                              unsigned* __restrict__ aggb, int c0, int cn) {
    int local = blockIdx.x * 4 + (threadIdx.x >> 6);
    int lane = threadIdx.x & 63;
    if (local >= cn) return;
    int n = c0 + local;
    int beg = n ? rowptr[n - 1] : 0;
    int end = rowptr[n];
    float acc[8][2];
#pragma unroll
    for (int r = 0; r < 8; ++r) { acc[r][0] = 0.f; acc[r][1] = 0.f; }
    int j = beg;
    for (; j + 8 <= end; j += 8) {  // 8 row-loads in flight
        int kk[8];
        unsigned uu[8];
#pragma unroll
        for (int q = 0; q < 8; ++q) kk[q] = pk[j + q];
#pragma unroll
        for (int q = 0; q < 8; ++q) uu[q] = xb[(size_t)(kk[q] >> 3) * 64 + lane];
#pragma unroll
        for (int q = 0; q < 8; ++q) addpk(acc, kk[q], uu[q]);
    }
    if (j + 4 <= end) {  // 4-deep mid tier
        int kk[4];
        unsigned uu[4];
#pragma unroll
        for (int q = 0; q < 4; ++q) kk[q] = pk[j + q];
#pragma unroll
        for (int q = 0; q < 4; ++q) uu[q] = xb[(size_t)(kk[q] >> 3) * 64 + lane];
#pragma unroll
        for (int q = 0; q < 4; ++q) addpk(acc, kk[q], uu[q]);
        j += 4;
    }
    for (; j < end; ++j) {
        int kk = pk[j];
        unsigned u = xb[(size_t)(kk >> 3) * 64 + lane];
        addpk(acc, kk, u);
    }
#pragma unroll
    for (int r = 0; r < 8; ++r)
        aggb[(size_t)local * 512 + r * 64 + lane] = packbf(acc[r][0], acc[r][1]);
}

// ---------- MFMA GEMM: out[n][d] = relu( sum_k A[n][k] Wb[d][k] + b[d] ), K=1152 ----------
// A = [aggb local rows, K=1024 bf16] ++ [xb_in global rows, K=128 bf16]
// 4 waves x 16 rows = 64 rows/block; LDS C-tile -> coalesced full-line stores.
__global__ __launch_bounds__(256) void k_mm2(const unsigned short* __restrict__ aggb,
                                             const unsigned short* __restrict__ xbin,
                                             const unsigned short* __restrict__ Wb,  // [128][1152]
                                             const float* __restrict__ bias,
                                             unsigned short* __restrict__ xbout,
                                             int c0, int cn) {
    __shared__ unsigned short Cs[64 * 128];  // 16 KB
    const int wv = threadIdx.x >> 6, lane = threadIdx.x & 63;
    const int r_in = lane & 15, kq = lane >> 4;
    const int lm0 = blockIdx.x * 64 + wv * 16;

    f32x4 acc[8];
#pragma unroll
    for (int cf = 0; cf < 8; ++cf) acc[cf] = (f32x4){0.f, 0.f, 0.f, 0.f};

    int la = lm0 + r_in;
    if (la >= cn) la = cn - 1;                      // clamp (stores masked below)
    const unsigned short* Arow = aggb + (size_t)la * 1024 + kq * 8;
    const unsigned short* Xrow = xbin + (size_t)(c0 + la) * 128 + kq * 8;
    const unsigned short* Brow = Wb + (size_t)r_in * 1152 + kq * 8;

#pragma unroll 1
    for (int ks = 0; ks < 36; ++ks) {
        const unsigned short* ap = (ks < 32) ? (Arow + ks * 32) : (Xrow + (ks - 32) * 32);
        bf16x8 a = *(const bf16x8*)ap;
#pragma unroll
        for (int cf = 0; cf < 8; ++cf) {
            bf16x8 b = *(const bf16x8*)(Brow + (size_t)cf * 16 * 1152 + ks * 32);
            acc[cf] = __builtin_amdgcn_mfma_f32_16x16x32_bf16(a, b, acc[cf], 0, 0, 0);
        }
    }
    // epilogue: bias+relu -> LDS C-tile (row = wv*16 + kq*4+reg, col = cf*16+r_in)
#pragma unroll
    for (int cf = 0; cf < 8; ++cf) {
        int d = cf * 16 + r_in;
        float bv = bias[d];
#pragma unroll
        for (int reg = 0; reg < 4; ++reg)
            Cs[(wv * 16 + kq * 4 + reg) * 128 + d] = f2bf(frelu(acc[cf][reg] + bv));
    }
    __syncthreads();
    // coalesced copy-out: 64 rows x 256B, 16B/thread, 4KB contiguous per iter
#pragma unroll
    for (int i = 0; i < 4; ++i) {
        int gidx = i * 256 + threadIdx.x;  // 0..1023
        int row = gidx >> 4, g16 = gidx & 15;
        int gr = blockIdx.x * 64 + row;
        if (gr < cn)
            *(int4*)((char*)xbout + (size_t)(c0 + gr) * 256 + g16 * 16) =
                *(const int4*)((const char*)Cs + row * 256 + g16 * 16);
    }
}

// ---------- column-wise sum/max over final bf16 x ----------
__global__ void k_reduce(const unsigned short* __restrict__ xb, float* __restrict__ gsum,
                         unsigned* __restrict__ gmax) {
    int c = threadIdx.x & 127;
    int half = threadIdx.x >> 7;
    int rbeg = blockIdx.x * 512 + half;
    int rend = min(blockIdx.x * 512 + 512, NN);
    float s = 0.f, m = 0.f;  // post-relu >= 0
    for (int r = rbeg; r < rend; r += 2) {
        float v = bf2f(xb[(size_t)r * 128 + c]);
        s += v;
        m = fmaxf(m, v);
    }
    atomicAdd(&gsum[c], s);
    atomicMax(&gmax[c], __float_as_uint(m));
}

// ---------- heads (single block), fp32 exact on fp32 head weights ----------
__global__ void k_head(const unsigned short* __restrict__ x, const float* __restrict__ gsum,
                       const unsigned* __restrict__ gmaxu, const int* __restrict__ anchor_idx,
                       const float* __restrict__ numeric, const float* __restrict__ boolean_,
                       const int* __restrict__ cats, const float* __restrict__ ce0,
                       const float* __restrict__ ce1, const float* __restrict__ ce2,
                       const float* __restrict__ featW, const float* __restrict__ featb,
                       const float* __restrict__ binW1, const float* __restrict__ binb1,
                       const float* __restrict__ binW2, const float* __restrict__ binb2,
                       const float* __restrict__ mcW1, const float* __restrict__ mcb1,
                       const float* __restrict__ mcW2, const float* __restrict__ mcb2,
                       float* __restrict__ out) {
    __shared__ float comb[432];
    __shared__ float feat[72];
    __shared__ float hb[4][64];
    int t = threadIdx.x;
    int anchor = anchor_idx[0];
    if (t < 128) {
        comb[t] = bf2f(x[(size_t)anchor * 128 + t]);
        comb[128 + t] = gsum[t] * (1.0f / (float)NN);
        comb[256 + t] = __uint_as_float(gmaxu[t]);
    }
    if (t < 32) feat[t] = numeric[t];
    else if (t < 48) feat[t] = boolean_[t - 32];
    else if (t < 56) feat[t] = ce0[cats[0] * 8 + (t - 48)];
    else if (t < 64) feat[t] = ce1[cats[1] * 8 + (t - 56)];
    else if (t < 72) feat[t] = ce2[cats[2] * 8 + (t - 64)];
    __syncthreads();
    if (t < 48) {
        float s = featb[t];
        for (int c = 0; c < 72; ++c) s += featW[t * 72 + c] * feat[c];
        comb[384 + t] = frelu(s);
    }
    __syncthreads();
    {
        int head = t >> 6, u = t & 63;
        const float* W;
        float s;
        if (head < 3) {
            W = binW1 + ((size_t)head * 64 + u) * 432;
            s = binb1[head * 64 + u];
        } else {
            W = mcW1 + (size_t)u * 432;
            s = mcb1[u];
        }
        for (int c = 0; c < 432; ++c) s += W[c] * comb[c];
        hb[head][u] = frelu(s);
    }
    __syncthreads();
    if (t < 3) {
        float s = binb2[t];
        for (int u = 0; u < 64; ++u) s += binW2[t * 64 + u] * hb[t][u];
        out[t] = s;
    } else if (t < 7) {
        int k = t - 3;
        float s = mcb2[k];
        for (int u = 0; u < 64; ++u) s += mcW2[k * 64 + u] * hb[3][u];
        out[3 + k] = s;
    }
}

extern "C" void kernel_launch(void* const* d_in, const int* in_sizes, int n_in,
                              void* d_out, int out_size, void* d_ws, size_t ws_size,
                              hipStream_t stream) {
    const int* ntype = (const int*)d_in[0];
    const int* eidx = (const int*)d_in[1];
    const int* etype = (const int*)d_in[2];
    const int* cats = (const int*)d_in[3];
    const int* anchor = (const int*)d_in[4];
    const float* numeric = (const float*)d_in[5];
    const float* boolean_ = (const float*)d_in[6];
    const float* nemb = (const float*)d_in[7];
    const float* selfW = (const float*)d_in[8];
    const float* selfb = (const float*)d_in[9];
    const float* relW = (const float*)d_in[10];
    const float* ce0 = (const float*)d_in[11];
    const float* ce1 = (const float*)d_in[12];
    const float* ce2 = (const float*)d_in[13];
    const float* featW = (const float*)d_in[14];
    const float* featb = (const float*)d_in[15];
    const float* binW1 = (const float*)d_in[16];
    const float* binb1 = (const float*)d_in[17];
    const float* binW2 = (const float*)d_in[18];
    const float* binb2 = (const float*)d_in[19];
    const float* mcW1 = (const float*)d_in[20];
    const float* mcb1 = (const float*)d_in[21];
    const float* mcW2 = (const float*)d_in[22];
    const float* mcb2 = (const float*)d_in[23];
    float* out = (float*)d_out;

    char* ws = (char*)d_ws;
    size_t off = 0;
    auto alloc = [&](size_t bytes) -> void* {
        void* pp = ws + off;
        off += (bytes + 255) & ~(size_t)255;
        return pp;
    };
    // fixed footprint ~66 MiB
    unsigned* xbA = (unsigned*)alloc((size_t)NN * 64 * 4);  // bf16 x, packed pairs
    unsigned* xbB = (unsigned*)alloc((size_t)NN * 64 * 4);
    int* rowptr = (int*)alloc((size_t)NN * 4);
    int* partials = (int*)alloc(4096);
    int* pkbuf = (int*)alloc((size_t)EE * 4);
    unsigned short* Wb = (unsigned short*)alloc((size_t)2 * 128 * 1152 * 2);
    float* gsum = (float*)alloc(512);
    unsigned* gmax = (unsigned*)alloc(512);
    // adaptive agg chunk: 2048 B per node (8 rel x 128 bf16)
    size_t avail = (ws_size > off) ? (ws_size - off) : 0;
    int chunk = (int)(avail / 2048);
    chunk &= ~63;                 // multiple of 64 for k_mm2 blocks
    if (chunk > NN) chunk = NN;
    if (chunk < 64) chunk = 64;   // ws below ~66 MiB is unrecoverable anyway
    unsigned* aggb = (unsigned*)(ws + off);
    (void)in_sizes; (void)n_in; (void)out_size;

    hipMemsetAsync(rowptr, 0, (size_t)NN * 4, stream);
    hipMemsetAsync(gsum, 0, 512, stream);
    hipMemsetAsync(gmax, 0, 512, stream);

    k_gather_xb<<<NN * 64 / 256, 256, 0, stream>>>(ntype, nemb, xbA);
    k_count<<<2048, 256, 0, stream>>>(eidx, rowptr);
    int nb1 = (NN + 1023) / 1024;
    k_scan1<<<nb1, 256, 0, stream>>>(rowptr, partials, NN);
    k_scan2<<<1, 1024, 0, stream>>>(partials, nb1);
    k_scan3<<<(NN + 255) / 256, 256, 0, stream>>>(rowptr, partials, NN);
    k_scatter<<<2048, 256, 0, stream>>>(eidx, etype, rowptr, pkbuf);
    k_prepWb<<<2 * 128 * 1152 / 256, 256, 0, stream>>>(relW, selfW, Wb);

    for (int l = 0; l < 2; ++l) {
        const unsigned* xin = l ? xbB : xbA;
        unsigned short* xout = (unsigned short*)(l ? xbA : xbB);
        const unsigned short* Wl = Wb + (size_t)l * 128 * 1152;
        const float* bl = selfb + l * 128;
        for (int c0 = 0; c0 < NN; c0 += chunk) {
            int cn = (NN - c0 < chunk) ? (NN - c0) : chunk;
            k_agg8<<<(cn + 3) / 4, 256, 0, stream>>>(xin, rowptr, pkbuf, aggb, c0, cn);
            k_mm2<<<(cn + 63) / 64, 256, 0, stream>>>((const unsigned short*)aggb,
                                                      (const unsigned short*)xin, Wl, bl,
                                                      xout, c0, cn);
        }
    }

    // final x is in xbA (layer 1 wrote to it)
    k_reduce<<<(NN + 511) / 512, 256, 0, stream>>>((const unsigned short*)xbA, gsum, gmax);
    k_head<<<1, 256, 0, stream>>>((const unsigned short*)xbA, gsum, gmax, anchor, numeric,
                                  boolean_, cats, ce0, ce1, ce2, featW, featb, binW1, binb1,
                                  binW2, binb2, mcW1, mcb1, mcW2, mcb2, out);
}